// Round 10
// baseline (36902.417 us; speedup 1.0000x reference)
//
#include <hip/hip_runtime.h>
#include <stdint.h>

#define T_STEPS 16384
#define NDIM 256
#define MDIM 512
#define KP1 512
#define LOUT 256
#define G 16
#define TPB 256
#define NBLK 256   // 1 block/CU; 16 workers on XCD 0, 240 keep-alive spinners

typedef unsigned long long u64;
typedef unsigned int u32;

// ---- ws layout (float offsets) ----
constexpr size_t OFF_GH    = 0;                         // [512][1536] cached W_hh@M[q]+b_hh
constexpr size_t OFF_GHS   = 512ull * 1536;             // [1536] scratch gh (q==0 / startup)
constexpr size_t OFF_M     = OFF_GHS + 1536;            // [512][512] memory rows
constexpr size_t OFF_RING  = OFF_M + 512ull * 512;      // [4][1536] gi ring
constexpr size_t OFF_H     = OFF_RING + 4ull * 1536;    // [16384][512] hidden outputs
constexpr size_t OFF_VWT   = OFF_H + 16384ull * 512;    // [512][256] V_w transposed
constexpr size_t OFF_FLAGS = OFF_VWT + 512ull * 256;    // 80 u64 agent flags (in-bounds)
// GH row 0 (6144B, q==0 never data): mode-1 spread flags, one 128B line each:
//   FB1[(p*16+i)*16]  u64   FC1 = FB1+512 (u64 idx)
// Mrow row 0 (2048B, q==0 never data): election scratch + done flag:
//   Ecnt=(u32*)Mrow; Tst=(u64*)(Mrow+16); Md=(u64*)(Mrow+64); Dn=(u64*)Mrow+96

// ---- agent-scope (MALL) ops — data path (R6/R9-proven fastest) ----
__device__ __forceinline__ float ld_cohf(const float* p) {
  return __hip_atomic_load(p, __ATOMIC_RELAXED, __HIP_MEMORY_SCOPE_AGENT);
}
__device__ __forceinline__ void st_cohf(float* p, float v) {
  __hip_atomic_store(p, v, __ATOMIC_RELAXED, __HIP_MEMORY_SCOPE_AGENT);
}
__device__ __forceinline__ u64 ld_flag(const u64* p) {
  return __hip_atomic_load(p, __ATOMIC_RELAXED, __HIP_MEMORY_SCOPE_AGENT);
}
__device__ __forceinline__ void st_flag_rel(u64* p, u64 v) {
  __hip_atomic_store(p, v, __ATOMIC_RELEASE, __HIP_MEMORY_SCOPE_AGENT);
}
__device__ __forceinline__ void st_flag_rlx(u64* p, u64 v) {
  __hip_atomic_store(p, v, __ATOMIC_RELAXED, __HIP_MEMORY_SCOPE_AGENT);
}

// ---- sc0 (XCD-L2 coherence point) flag ops — only after qualification ----
__device__ __forceinline__ u64 ld64_sc0(const u64* p) {
  u64 v;
  asm volatile("global_load_dwordx2 %0, %1, off sc0\n\t"
               "s_waitcnt vmcnt(0)"
               : "=&v"(v) : "v"(p) : "memory");
  return v;
}
__device__ __forceinline__ void st64_sc0(u64* p, u64 v) {
  asm volatile("global_store_dwordx2 %0, %1, off sc0" :: "v"(p), "v"(v) : "memory");
}
__device__ __forceinline__ void drain_vm() {
  asm volatile("s_waitcnt vmcnt(0)" ::: "memory");
}

// HW_REG_XCC_ID = 20 (gfx940+)
#define HWREG_XCC_ID ((31u << 11) | 20u)
__device__ __forceinline__ u32 xcc_id() {
  return (u32)__builtin_amdgcn_s_getreg(HWREG_XCC_ID) & 0xFu;
}

__device__ __forceinline__ float sigm(float x) {
  return __builtin_amdgcn_rcpf(1.0f + __expf(-x));
}
__device__ __forceinline__ float tanh_(float x) {
  return 1.0f - 2.0f * __builtin_amdgcn_rcpf(__expf(2.0f * x) + 1.0f);
}

// ---- DPP max-reduce helpers ----
template<int CTRL>
__device__ __forceinline__ u32 dppmax(u32 v) {
  u32 t = (u32)__builtin_amdgcn_update_dpp(0, (int)v, CTRL, 0xf, 0xf, true);
  return v > t ? v : t;
}
__device__ __forceinline__ u32 wave_max_u32(u32 v) {
  v = dppmax<0x111>(v);
  v = dppmax<0x112>(v);
  v = dppmax<0x114>(v);
  v = dppmax<0x118>(v);
  v = dppmax<0x142>(v);
  v = dppmax<0x143>(v);
  return (u32)__builtin_amdgcn_readlane((int)v, 63);
}
__device__ __forceinline__ u32 row16_max_u32(u32 v) {
  v = dppmax<0x111>(v);
  v = dppmax<0x112>(v);
  v = dppmax<0x114>(v);
  v = dppmax<0x118>(v);
  return (u32)__builtin_amdgcn_readlane((int)v, 15);
}

__global__ __launch_bounds__(TPB, 1) void dmm_main(
    const float* __restrict__ X, const float* __restrict__ h0,
    const float* __restrict__ W_ih, const float* __restrict__ W_hh,
    const float* __restrict__ b_ih, const float* __restrict__ b_hh,
    const float* __restrict__ C_w, const float* __restrict__ C_b,
    float* __restrict__ ws)
{
  const int tid = threadIdx.x;
  const int w   = tid >> 6;
  const int l   = tid & 63;

  float* GH   = ws + OFF_GH;
  float* GHS  = ws + OFF_GHS;
  float* Mrow = ws + OFF_M;
  float* RING = ws + OFF_RING;
  float* H    = ws + OFF_H;
  u64*   F    = (u64*)(ws + OFF_FLAGS);
  u64*   FB1  = (u64*)(ws + OFF_GH);         // mode-1 spread flagB (GH row 0)
  u64*   FC1  = (u64*)(ws + OFF_GH) + 512;   // mode-1 spread flagC

  u32* Ecnt = (u32*)Mrow;
  u64* Tst  = (u64*)(Mrow + 16);
  u64* Md   = (u64*)(Mrow + 64);
  u64* Dn   = (u64*)Mrow + 96;               // done flag (byte 768, zeroed)

  __shared__ __align__(16) float hnew[MDIM];
  __shared__ __align__(16) float red[96 * 36];
  __shared__ u32 written[KP1];
  __shared__ u32 bcw;
  __shared__ int s_i;

  // ---- election: first G blocks on XCD 0 become workers ----
  if (tid == 0) {
    u32 xcc = xcc_id();
    int widx = -1;
    if (xcc == 0) {
      u32 r = __hip_atomic_fetch_add(Ecnt, 1u, __ATOMIC_RELAXED,
                                     __HIP_MEMORY_SCOPE_AGENT);
      if (r < (u32)G) widx = (int)r;
    } else if (blockIdx.x < G) {
      int guard = 0; u32 c;
      do {
        c = __hip_atomic_load(Ecnt, __ATOMIC_RELAXED, __HIP_MEMORY_SCOPE_AGENT);
      } while (c < (u32)G && ++guard < (1 << 12));
      if (c < (u32)G) {
        u32 r = __hip_atomic_fetch_add(Ecnt, 1u, __ATOMIC_RELAXED,
                                       __HIP_MEMORY_SCOPE_AGENT);
        if (r < (u32)G) widx = (int)r;
      }
    }
    s_i = widx;
  }
  __syncthreads();
  const int b = s_i;
  __syncthreads();

  if (b < 0) {
    // ---- keep-alive spinner: pin SCLK while workers run (DVFS guard) ----
    // dependent-FMA chain (~25% VALU duty, zero memory traffic) +
    // one agent-scope done-flag poll per ~0.9us quantum per wave.
    float a0 = (float)(tid + 1) * 1.0e-3f;
    for (int it = 0; it < (1 << 17); ++it) {      // ~110ms hard bound
#pragma unroll 1
      for (int k = 0; k < 512; ++k)
        a0 = fmaf(a0, 1.0000001f, 1.0e-7f);
      asm volatile("" :: "v"(a0));                // keep chain live
      if (__hip_atomic_load(Dn, __ATOMIC_RELAXED, __HIP_MEMORY_SCOPE_AGENT))
        break;
    }
    return;
  }

  // ---- sc0 qualification: 8-round monotone ping-pong; timeout -> agent mode ----
  __shared__ int s_good;
  if (tid == 0) s_good = 1;
  __syncthreads();
  for (int r = 1; r <= 8; ++r) {
    if (tid == 0 && s_good) {
      drain_vm();
      st64_sc0(&Tst[b], (u64)r);
    }
    if (w == 0 && s_good) {
      int guard = 0;
      for (;;) {
        u64 v = (u64)r;
        if (l < G) v = ld64_sc0(&Tst[l]);
        bool ok = (l >= G) || (v >= (u64)r);
        if (__ballot((int)ok) == ~0ull) break;
        if (++guard > (1 << 12)) { if (l == 0) s_good = 0; break; }
      }
    }
    __syncthreads();
  }
  if (tid == 0)
    __hip_atomic_store(&Md[b], 2ull | (u64)s_good, __ATOMIC_RELEASE,
                       __HIP_MEMORY_SCOPE_AGENT);
  if (w == 0) {
    int guard = 0, moderes = 0;
    for (;;) {
      u64 v = 3ull;
      if (l < G) v = __hip_atomic_load(&Md[l], __ATOMIC_ACQUIRE,
                                       __HIP_MEMORY_SCOPE_AGENT);
      bool ok = (l >= G) || ((v & 2ull) != 0);
      if (__ballot((int)ok) == ~0ull) {
        u64 bm = __ballot((int)((v & 1ull) != 0));
        moderes = (bm == ~0ull) ? 1 : 0;
        break;
      }
      if (++guard > (1 << 20)) { moderes = 0; break; }
    }
    if (l == 0) s_i = moderes;
  }
  __syncthreads();
  const bool SC0F = (s_i != 0);      // block-uniform mode
  const int GSTEP = SC0F ? (1 << 12) : (1 << 22);

  // ================= body: R9 (agent data + sc0 spread flags) ===============

  const int pw   = (w >= 1) ? (w - 1) : 0;
  const int rloc = pw * 32 + (l >> 4) * 8;
  float wih[8][16];
  {
    int rbase = 96 * b + rloc;
    int cbase = 16 * (l & 15);
#pragma unroll
    for (int i = 0; i < 8; i++)
#pragma unroll
      for (int k = 0; k < 16; k++)
        wih[i][k] = W_ih[(size_t)(rbase + i) * NDIM + cbase + k];
  }
  float bihr[8];
#pragma unroll
  for (int i = 0; i < 8; i++) bihr[i] = b_ih[96 * b + rloc + i];

  float cw[4][16];
  {
    int rbase = 32 * b + w * 8 + (l >> 5) * 4;
    int cbase = 16 * (l & 31);
#pragma unroll
    for (int i = 0; i < 4; i++)
#pragma unroll
      for (int k = 0; k < 16; k++)
        cw[i][k] = C_w[(size_t)(rbase + i) * MDIM + cbase + k];
  }

  for (int i = tid; i < KP1; i += TPB) written[i] = 0u;
  if (tid == 0) bcw = 0u;
  hnew[tid]       = h0[tid];
  hnew[tid + 256] = h0[tid + 256];
  __syncthreads();

  float xreg[16];
  auto prefetchX = [&](int s) {
    int cbase = 16 * (l & 15);
    const float* xp = &X[(size_t)s * NDIM + cbase];
    if (SC0F) {
#pragma unroll
      for (int k = 0; k < 16; k++) xreg[k] = __builtin_nontemporal_load(&xp[k]);
    } else {
#pragma unroll
      for (int k = 0; k < 16; k++) xreg[k] = xp[k];
    }
  };

  auto produce_gi = [&](int s) {
    float p[8];
#pragma unroll
    for (int i = 0; i < 8; i++) {
      float a = 0.f;
#pragma unroll
      for (int k = 0; k < 16; k++) a = fmaf(wih[i][k], xreg[k], a);
      p[i] = a;
    }
#pragma unroll
    for (int off = 1; off <= 8; off <<= 1) {
#pragma unroll
      for (int i = 0; i < 8; i++) p[i] += __shfl_xor(p[i], off, 64);
    }
    if ((l & 15) == 0) {
      float* dst = &RING[(size_t)(s & 3) * 1536 + 96 * b + rloc];
#pragma unroll
      for (int i = 0; i < 8; i++) st_cohf(&dst[i], p[i] + bihr[i]);
    }
  };

  auto compute_gh = [&](float* dst) {
    int cb = 16 * (l & 31);
    float hr[16];
#pragma unroll
    for (int k = 0; k < 16; k += 4) *(float4*)&hr[k] = *(const float4*)&hnew[cb + k];
    int rb = 96 * b + w * 24 + (l >> 5) * 12;
    float p[12];
#pragma unroll
    for (int i = 0; i < 12; i++) {
      float a = 0.f;
      const float* wr = &W_hh[(size_t)(rb + i) * MDIM + cb];
#pragma unroll
      for (int k = 0; k < 16; k++) a = fmaf(wr[k], hr[k], a);
      p[i] = a;
    }
    int rl = w * 24 + (l >> 5) * 12;
    int lc = l & 31;
#pragma unroll
    for (int i = 0; i < 12; i++) red[(rl + i) * 36 + lc] = p[i];
    __syncthreads();
    if (tid < 96) {
      float a = 0.f;
#pragma unroll
      for (int k = 0; k < 32; k += 4) {
        float4 v = *(const float4*)&red[tid * 36 + k];
        a += v.x + v.y + v.z + v.w;
      }
      a += b_hh[96 * b + tid];
      st_cohf(&dst[96 * b + tid], a);
    }
    __syncthreads();   // compiler drains vmcnt before barrier -> data at MALL
  };

  // ---- startup ----
  if (w >= 1) {
    prefetchX(0); produce_gi(0);
    prefetchX(1); produce_gi(1);
    prefetchX(2); produce_gi(2);
    prefetchX(3);
  }
  __syncthreads();
  compute_gh(GHS);
  if (tid == 0) st_flag_rel(&F[b], 1ull);
  if (w == 0) {
    int guard = 0;
    for (;;) {
      u64 v = (l < G) ? ld_flag(&F[l]) : 1ull;
      if (__ballot((int)(v == 1ull)) == ~0ull) break;
      if (++guard > (1 << 22)) break;
    }
  }
  __syncthreads();

  const float* ghsrc = GHS;
  bool prevReadHit = false;
  int  qprev = 0;

  for (int t = 0; t < T_STEPS; ++t) {
    // ---- agent-scope load bundle ----
    float g0 = ld_cohf(&ghsrc[tid]);
    float g1 = ld_cohf(&ghsrc[tid + 256]);
    float g2 = ld_cohf(&ghsrc[512 + tid]);
    float g3 = ld_cohf(&ghsrc[512 + tid + 256]);
    float g4 = ld_cohf(&ghsrc[1024 + tid]);
    float g5 = ld_cohf(&ghsrc[1024 + tid + 256]);
    float m0 = 0.f, m1 = 0.f;
    if (prevReadHit) {
      m0 = ld_cohf(&Mrow[(size_t)qprev * 512 + tid]);
      m1 = ld_cohf(&Mrow[(size_t)qprev * 512 + tid + 256]);
    }
    const float* gi = &RING[(size_t)(t & 3) * 1536];
    float i0 = ld_cohf(&gi[tid]);
    float i1 = ld_cohf(&gi[tid + 256]);
    float i2 = ld_cohf(&gi[512 + tid]);
    float i3 = ld_cohf(&gi[512 + tid + 256]);
    float i4 = ld_cohf(&gi[1024 + tid]);
    float i5 = ld_cohf(&gi[1024 + tid + 256]);

    if (prevReadHit && b == 0) {
      __builtin_nontemporal_store(m0, &H[(size_t)(t - 1) * 512 + tid]);
      __builtin_nontemporal_store(m1, &H[(size_t)(t - 1) * 512 + tid + 256]);
    }

    float hp0 = prevReadHit ? m0 : hnew[tid];
    float hp1 = prevReadHit ? m1 : hnew[tid + 256];
    float r0 = sigm(i0 + g0), r1 = sigm(i1 + g1);
    float z0 = sigm(i2 + g2), z1 = sigm(i3 + g3);
    float n0 = tanh_(fmaf(r0, g4, i4)), n1 = tanh_(fmaf(r1, g5, i5));
    float hn0 = fmaf(z0, hp0 - n0, n0);
    float hn1 = fmaf(z1, hp1 - n1, n1);
    hnew[tid]       = hn0;
    hnew[tid + 256] = hn1;
    __syncthreads();                               // B1

    {
      int cb = 16 * (l & 31);
      float hr[16];
#pragma unroll
      for (int k = 0; k < 16; k += 4) *(float4*)&hr[k] = *(const float4*)&hnew[cb + k];
      float p0 = 0.f, p1 = 0.f, p2 = 0.f, p3 = 0.f;
#pragma unroll
      for (int k = 0; k < 16; k++) {
        p0 = fmaf(cw[0][k], hr[k], p0);
        p1 = fmaf(cw[1][k], hr[k], p1);
        p2 = fmaf(cw[2][k], hr[k], p2);
        p3 = fmaf(cw[3][k], hr[k], p3);
      }
      int rl = w * 8 + (l >> 5) * 4;
      int lc = l & 31;
      red[(rl + 0) * 36 + lc] = p0;
      red[(rl + 1) * 36 + lc] = p1;
      red[(rl + 2) * 36 + lc] = p2;
      red[(rl + 3) * 36 + lc] = p3;
    }
    __syncthreads();                               // B2

    u64 ownkey = 0;
    if (w <= 1) {
      u32 ord = 0;
      if (l < 32) {
        const float4* rp = (const float4*)&red[l * 36];
        float4 v0 = rp[0], v1 = rp[1], v2 = rp[2], v3 = rp[3];
        float4 v4 = rp[4], v5 = rp[5], v6 = rp[6], v7 = rp[7];
        double d0 = ((double)v0.x + (double)v0.y) + ((double)v0.z + (double)v0.w);
        double d1 = ((double)v1.x + (double)v1.y) + ((double)v1.z + (double)v1.w);
        double d2 = ((double)v2.x + (double)v2.y) + ((double)v2.z + (double)v2.w);
        double d3 = ((double)v3.x + (double)v3.y) + ((double)v3.z + (double)v3.w);
        double d4 = ((double)v4.x + (double)v4.y) + ((double)v4.z + (double)v4.w);
        double d5 = ((double)v5.x + (double)v5.y) + ((double)v5.z + (double)v5.w);
        double d6 = ((double)v6.x + (double)v6.y) + ((double)v6.z + (double)v6.w);
        double d7 = ((double)v7.x + (double)v7.y) + ((double)v7.z + (double)v7.w);
        double a = (((d0 + d1) + (d2 + d3)) + ((d4 + d5) + (d6 + d7)))
                 + (double)C_b[32 * b + l];
        float af = (float)a;
        u32 bits = __float_as_uint(af);
        ord = (bits & 0x80000000u) ? ~bits : (bits | 0x80000000u);
      }
      u32 maxord = wave_max_u32(ord);
      u64 mask = __ballot((int)(ord == maxord));
      int lane = __builtin_ctzll(mask);
      u64 key41 = ((u64)maxord << 9) | (u64)(511 - (32 * b + lane));
      if (tid == 64) {
        u64 fv = ((u64)(t + 1) << 41) | key41;
        if (SC0F) st64_sc0(&FB1[((size_t)(t & 1) * 16 + b) * 16], fv);
        else      st_flag_rlx(&F[16 + (size_t)(t & 1) * 16 + b], fv);
      }
      ownkey = key41;
    }

    if (w >= 1 && t + 3 < T_STEPS) {
      produce_gi(t + 3);
      if (t + 4 < T_STEPS) prefetchX(t + 4);
    }

    u32 info;
    if (w == 0) {
      const bool need = (l < G) && (l != b);
      u64 v = 0;
      if (SC0F) {
        // ---- pipelined 2-deep sc0 poll ----
        drain_vm();
        const u64* fp = &FB1[((size_t)(t & 1) * 16 + l) * 16];
        u64 va = 0, vb = 0;
        if (need)
          asm volatile("global_load_dwordx2 %0, %2, off sc0\n\t"
                       "global_load_dwordx2 %1, %2, off sc0"
                       : "=&v"(va), "=&v"(vb) : "v"(fp) : "memory");
        int guard = 0;
        for (;;) {
          asm volatile("s_waitcnt vmcnt(1)" ::: "memory");
          bool ok = !need || ((va >> 41) == (u64)(t + 1));
          if (__ballot((int)ok) == ~0ull) { v = va; break; }
          if (need)
            asm volatile("global_load_dwordx2 %0, %1, off sc0"
                         : "=&v"(va) : "v"(fp) : "memory");
          asm volatile("s_waitcnt vmcnt(1)" ::: "memory");
          ok = !need || ((vb >> 41) == (u64)(t + 1));
          if (__ballot((int)ok) == ~0ull) { v = vb; break; }
          if (need)
            asm volatile("global_load_dwordx2 %0, %1, off sc0"
                         : "=&v"(vb) : "v"(fp) : "memory");
          if (++guard > GSTEP) { v = va; break; }
        }
        drain_vm();
      } else {
        const u64* fp = &F[16 + (size_t)(t & 1) * 16 + l];
        u64 vp = need ? ld_flag(fp) : 0;
        int guard = 0;
        for (;;) {
          u64 vn = need ? ld_flag(fp) : 0;
          bool ok = !need || ((vp >> 41) == (u64)(t + 1));
          if (__ballot((int)ok) == ~0ull) { v = vp; break; }
          vp = vn;
          if (++guard > GSTEP) { v = vp; break; }
        }
      }
      u64 key = (l < G) ? ((l == b) ? ownkey : (v & ((1ull << 41) - 1))) : 0;
      u32 o = (u32)(key >> 9);
      u32 maxo = row16_max_u32(o);
      u32 cand = (o == maxo && l < G) ? (u32)(key & 511u) : 0u;
      u32 best = row16_max_u32(cand);
      int q = 511 - (int)best;
      u32 vinfo = 0;
      if (l == 0) {
        u32 wr = written[q];
        u32 fresh = (q > 0 && wr == 0u) ? 1u : 0u;
        u32 rhit  = (q > 0 && wr != 0u) ? 1u : 0u;
        if (fresh) written[q] = 1u;
        vinfo = (u32)q | (fresh << 16) | (rhit << 17);
      }
      vinfo = (u32)__builtin_amdgcn_readfirstlane((int)vinfo);
      info = vinfo;
      if (l == 0)
        __hip_atomic_store(&bcw, (vinfo << 4) | ((u32)(t + 1) & 0xFu),
                           __ATOMIC_RELEASE, __HIP_MEMORY_SCOPE_WORKGROUP);
    } else {
      u32 v;
      int guard = 0;
      for (;;) {
        v = __hip_atomic_load(&bcw, __ATOMIC_ACQUIRE, __HIP_MEMORY_SCOPE_WORKGROUP);
        if ((v & 0xFu) == ((u32)(t + 1) & 0xFu)) break;
        if (++guard > (1 << 25)) break;
      }
      info = v >> 4;
    }
    int  q     = (int)(info & 0xFFFFu);
    bool fresh = (info >> 16) & 1u;
    bool rhit  = (info >> 17) & 1u;

    if (!rhit) {
      if (b == 0) {
        __builtin_nontemporal_store(hnew[tid], &H[(size_t)t * 512 + tid]);
        __builtin_nontemporal_store(hnew[tid + 256], &H[(size_t)t * 512 + tid + 256]);
      }
      float* dst;
      if (fresh) {
        if (tid < 32) st_cohf(&Mrow[(size_t)q * 512 + 32 * b + tid], hnew[32 * b + tid]);
        dst = &GH[(size_t)q * 1536];
      } else {
        dst = GHS;
      }
      compute_gh(dst);
      if (tid == 0) {
        if (SC0F) st64_sc0(&FC1[(size_t)b * 16], (u64)(t + 1));
        else      st_flag_rel(&F[48 + (size_t)(t & 1) * 16 + b], (u64)(t + 1));
      }
      if (w == 0) {
        int guard = 0;
        for (;;) {
          u64 v = (u64)(t + 1);
          if (l < G) {
            if (SC0F) v = ld64_sc0(&FC1[(size_t)l * 16]);
            else      v = ld_flag(&F[48 + (size_t)(t & 1) * 16 + l]);
          }
          bool ok = (l >= G) || (v == (u64)(t + 1));
          if (__ballot((int)ok) == ~0ull) break;
          if (++guard > GSTEP) break;
        }
      }
      __syncthreads();
      ghsrc = dst;
      prevReadHit = false;
    } else {
      ghsrc = &GH[(size_t)q * 1536];
      prevReadHit = true;
      qprev = q;
    }
  }

  // epilogue: H[T-1] for trailing read-hit (single writer)
  if (prevReadHit && b == 0) {
    float a = ld_cohf(&Mrow[(size_t)qprev * 512 + tid]);
    float c = ld_cohf(&Mrow[(size_t)qprev * 512 + tid + 256]);
    __builtin_nontemporal_store(a, &H[(size_t)(T_STEPS - 1) * 512 + tid]);
    __builtin_nontemporal_store(c, &H[(size_t)(T_STEPS - 1) * 512 + tid + 256]);
  }
  // release the keep-alive spinners
  if (b == 0 && tid == 0) st_flag_rel(Dn, 1ull);
}

// ---- V_w transpose (+ zero election scratch and mode-1 flag area) ----
__global__ void vw_transpose(const float* __restrict__ Vw, float* __restrict__ VwT) {
  int idx = blockIdx.x * 256 + threadIdx.x;
  if (blockIdx.x == 0) {
    float* M0 = VwT - (OFF_VWT - OFF_M);   // ws + OFF_M (row 0, never data)
    M0[threadIdx.x] = 0.f;
    M0[threadIdx.x + 256] = 0.f;
  }
  if (blockIdx.x == 1) {
    float* G0 = VwT - OFF_VWT;             // ws + OFF_GH (row 0, never data)
#pragma unroll
    for (int i = 0; i < 6; i++) G0[threadIdx.x + 256 * i] = 0.f;
  }
  int kk = idx >> 8, ll = idx & 255;
  VwT[idx] = Vw[(size_t)ll * MDIM + kk];
}

// ---- Y = H @ V_w^T + V_b ----
__global__ __launch_bounds__(256) void y_gemm(const float* __restrict__ Hm,
                                              const float* __restrict__ VwT,
                                              const float* __restrict__ Vb,
                                              float* __restrict__ Y) {
  int t0 = blockIdx.x * 16;
  int tid = threadIdx.x;
  __shared__ __align__(16) float hs[16 * MDIM];
  for (int i = tid; i < 16 * MDIM; i += 256)
    hs[i] = Hm[(size_t)t0 * MDIM + i];
  __syncthreads();
  float acc[16];
  float vb = Vb[tid];
#pragma unroll
  for (int r = 0; r < 16; r++) acc[r] = vb;
  for (int k = 0; k < MDIM; k += 4) {
    float v0 = VwT[(size_t)(k + 0) * LOUT + tid];
    float v1 = VwT[(size_t)(k + 1) * LOUT + tid];
    float v2 = VwT[(size_t)(k + 2) * LOUT + tid];
    float v3 = VwT[(size_t)(k + 3) * LOUT + tid];
#pragma unroll
    for (int r = 0; r < 16; r++) {
      float4 h4 = *(const float4*)&hs[r * MDIM + k];
      acc[r] = fmaf(h4.x, v0, fmaf(h4.y, v1, fmaf(h4.z, v2, fmaf(h4.w, v3, acc[r]))));
    }
  }
#pragma unroll
  for (int r = 0; r < 16; r++)
    Y[(size_t)(t0 + r) * LOUT + tid] = acc[r];
}

extern "C" void kernel_launch(void* const* d_in, const int* in_sizes, int n_in,
                              void* d_out, int out_size, void* d_ws, size_t ws_size,
                              hipStream_t stream) {
  const float* X    = (const float*)d_in[0];
  const float* h0   = (const float*)d_in[1];
  const float* W_ih = (const float*)d_in[2];
  const float* W_hh = (const float*)d_in[3];
  const float* b_ih = (const float*)d_in[4];
  const float* b_hh = (const float*)d_in[5];
  const float* C_w  = (const float*)d_in[6];
  const float* C_b  = (const float*)d_in[7];
  const float* V_w  = (const float*)d_in[8];
  const float* V_b  = (const float*)d_in[9];
  float* ws  = (float*)d_ws;
  float* VwT = ws + OFF_VWT;
  float* Hm  = ws + OFF_H;

  hipLaunchKernelGGL(vw_transpose, dim3(512), dim3(256), 0, stream, V_w, VwT);
  hipLaunchKernelGGL(dmm_main, dim3(NBLK), dim3(TPB), 0, stream,
                     X, h0, W_ih, W_hh, b_ih, b_hh, C_w, C_b, ws);
  hipLaunchKernelGGL(y_gemm, dim3(T_STEPS / 16), dim3(256), 0, stream,
                     Hm, VwT, V_b, (float*)d_out);
}

// Round 11
// 36648.889 us; speedup vs baseline: 1.0069x; 1.0069x over previous
//
#include <hip/hip_runtime.h>
#include <stdint.h>

#define T_STEPS 16384
#define NDIM 256
#define MDIM 512
#define KP1 512
#define LOUT 256
#define G 16
#define TPB 256
#define NBLK 256   // 1 block/CU; 16 workers on XCD 0; others = fabric keep-alive

typedef unsigned long long u64;
typedef unsigned int u32;

// ---- ws layout (float offsets) ----
constexpr size_t OFF_GH    = 0;                         // [512][1536] cached W_hh@M[q]+b_hh
constexpr size_t OFF_GHS   = 512ull * 1536;             // [1536] scratch gh (q==0 / startup)
constexpr size_t OFF_M     = OFF_GHS + 1536;            // [512][512] memory rows
constexpr size_t OFF_RING  = OFF_M + 512ull * 512;      // [4][1536] gi ring
constexpr size_t OFF_H     = OFF_RING + 4ull * 1536;    // [16384][512] hidden outputs
constexpr size_t OFF_VWT   = OFF_H + 16384ull * 512;    // [512][256] V_w transposed
constexpr size_t OFF_FLAGS = OFF_VWT + 512ull * 256;    // 80 u64 agent flags (in-bounds)
// GH row 0 (6144B, q==0 never data): mode-1 spread flags, one 128B line each:
//   FB1[(p*16+i)*16]  u64   FC1 = FB1+512 (u64 idx)
// Mrow row 0 (2048B, q==0 never data): election scratch + done flag:
//   Ecnt=(u32*)Mrow; Tst=(u64*)(Mrow+16); Md=(u64*)(Mrow+64); Dn=(u64*)Mrow+96

// ---- agent-scope (MALL) ops — data path (R6/R9-proven fastest) ----
__device__ __forceinline__ float ld_cohf(const float* p) {
  return __hip_atomic_load(p, __ATOMIC_RELAXED, __HIP_MEMORY_SCOPE_AGENT);
}
__device__ __forceinline__ void st_cohf(float* p, float v) {
  __hip_atomic_store(p, v, __ATOMIC_RELAXED, __HIP_MEMORY_SCOPE_AGENT);
}
__device__ __forceinline__ u64 ld_flag(const u64* p) {
  return __hip_atomic_load(p, __ATOMIC_RELAXED, __HIP_MEMORY_SCOPE_AGENT);
}
__device__ __forceinline__ void st_flag_rel(u64* p, u64 v) {
  __hip_atomic_store(p, v, __ATOMIC_RELEASE, __HIP_MEMORY_SCOPE_AGENT);
}
__device__ __forceinline__ void st_flag_rlx(u64* p, u64 v) {
  __hip_atomic_store(p, v, __ATOMIC_RELAXED, __HIP_MEMORY_SCOPE_AGENT);
}

// ---- sc0 (XCD-L2 coherence point) flag ops — only after qualification ----
__device__ __forceinline__ u64 ld64_sc0(const u64* p) {
  u64 v;
  asm volatile("global_load_dwordx2 %0, %1, off sc0\n\t"
               "s_waitcnt vmcnt(0)"
               : "=&v"(v) : "v"(p) : "memory");
  return v;
}
__device__ __forceinline__ void st64_sc0(u64* p, u64 v) {
  asm volatile("global_store_dwordx2 %0, %1, off sc0" :: "v"(p), "v"(v) : "memory");
}
__device__ __forceinline__ void drain_vm() {
  asm volatile("s_waitcnt vmcnt(0)" ::: "memory");
}

// HW_REG_XCC_ID = 20 (gfx940+)
#define HWREG_XCC_ID ((31u << 11) | 20u)
__device__ __forceinline__ u32 xcc_id() {
  return (u32)__builtin_amdgcn_s_getreg(HWREG_XCC_ID) & 0xFu;
}

__device__ __forceinline__ float sigm(float x) {
  return __builtin_amdgcn_rcpf(1.0f + __expf(-x));
}
__device__ __forceinline__ float tanh_(float x) {
  return 1.0f - 2.0f * __builtin_amdgcn_rcpf(__expf(2.0f * x) + 1.0f);
}

// ---- DPP max-reduce helpers ----
template<int CTRL>
__device__ __forceinline__ u32 dppmax(u32 v) {
  u32 t = (u32)__builtin_amdgcn_update_dpp(0, (int)v, CTRL, 0xf, 0xf, true);
  return v > t ? v : t;
}
__device__ __forceinline__ u32 wave_max_u32(u32 v) {
  v = dppmax<0x111>(v);
  v = dppmax<0x112>(v);
  v = dppmax<0x114>(v);
  v = dppmax<0x118>(v);
  v = dppmax<0x142>(v);
  v = dppmax<0x143>(v);
  return (u32)__builtin_amdgcn_readlane((int)v, 63);
}
__device__ __forceinline__ u32 row16_max_u32(u32 v) {
  v = dppmax<0x111>(v);
  v = dppmax<0x112>(v);
  v = dppmax<0x114>(v);
  v = dppmax<0x118>(v);
  return (u32)__builtin_amdgcn_readlane((int)v, 15);
}

__global__ __launch_bounds__(TPB, 1) void dmm_main(
    const float* __restrict__ X, const float* __restrict__ h0,
    const float* __restrict__ W_ih, const float* __restrict__ W_hh,
    const float* __restrict__ b_ih, const float* __restrict__ b_hh,
    const float* __restrict__ C_w, const float* __restrict__ C_b,
    float* __restrict__ ws)
{
  const int tid = threadIdx.x;
  const int w   = tid >> 6;
  const int l   = tid & 63;

  float* GH   = ws + OFF_GH;
  float* GHS  = ws + OFF_GHS;
  float* Mrow = ws + OFF_M;
  float* RING = ws + OFF_RING;
  float* H    = ws + OFF_H;
  u64*   F    = (u64*)(ws + OFF_FLAGS);
  u64*   FB1  = (u64*)(ws + OFF_GH);         // mode-1 spread flagB (GH row 0)
  u64*   FC1  = (u64*)(ws + OFF_GH) + 512;   // mode-1 spread flagC

  u32* Ecnt = (u32*)Mrow;
  u64* Tst  = (u64*)(Mrow + 16);
  u64* Md   = (u64*)(Mrow + 64);
  u64* Dn   = (u64*)Mrow + 96;               // done flag (byte 768, zeroed)

  __shared__ __align__(16) float hnew[MDIM];
  __shared__ __align__(16) float red[96 * 36];
  __shared__ u32 written[KP1];
  __shared__ u32 bcw;
  __shared__ int s_i;

  // ---- election: first G blocks on XCD 0 become workers ----
  if (tid == 0) {
    u32 xcc = xcc_id();
    int widx = -1;
    if (xcc == 0) {
      u32 r = __hip_atomic_fetch_add(Ecnt, 1u, __ATOMIC_RELAXED,
                                     __HIP_MEMORY_SCOPE_AGENT);
      if (r < (u32)G) widx = (int)r;
    } else if (blockIdx.x < G) {
      int guard = 0; u32 c;
      do {
        c = __hip_atomic_load(Ecnt, __ATOMIC_RELAXED, __HIP_MEMORY_SCOPE_AGENT);
      } while (c < (u32)G && ++guard < (1 << 12));
      if (c < (u32)G) {
        u32 r = __hip_atomic_fetch_add(Ecnt, 1u, __ATOMIC_RELAXED,
                                       __HIP_MEMORY_SCOPE_AGENT);
        if (r < (u32)G) widx = (int)r;
      }
    }
    s_i = widx;
  }
  __syncthreads();
  const int b = s_i;
  __syncthreads();

  if (b < 0) {
    // ---- keep-alive: pin the FABRIC (FCLK/MALL), not just SCLK ----
    // R10 falsified SCLK-DVFS (VALU spinners, no effect). The slow-mode
    // signature (uniform 1.7x latency inflation at identical counters) and
    // the 2x-inflated per-step RTT budget both point at the fabric clock
    // domain: the workers' 24 GB/s demand lets FCLK droop. Non-workers on
    // XCD!=0 stream moderate nt reads of X (~0.5-1 TB/s aggregate) to hold
    // the fabric up; XCD-0 non-workers stay VALU-only (off the workers'
    // L2 crossbar).
    u32 xcc = xcc_id();
    float a0 = (float)(tid + 1) * 1.0e-3f;
    if (xcc != 0) {
      const char* xb = (const char*)X;
      float acc = 0.f;
      for (int it = 0; it < (1 << 17); ++it) {
        u32 off = ((u32)blockIdx.x * 2654435761u + (u32)it * 1664525u)
                  & 0x7FF000u;                       // 4KB-aligned, < 8MB
        const float* xp = (const float*)(xb + off + (u32)tid * 16u);
        float v0 = __builtin_nontemporal_load(&xp[0]);
        float v1 = __builtin_nontemporal_load(&xp[1]);
        float v2 = __builtin_nontemporal_load(&xp[2]);
        float v3 = __builtin_nontemporal_load(&xp[3]);
        acc += (v0 + v1) + (v2 + v3);
#pragma unroll 1
        for (int k = 0; k < 512; ++k)
          a0 = fmaf(a0, 1.0000001f, 1.0e-7f);
        asm volatile("" :: "v"(a0), "v"(acc));
        if (__hip_atomic_load(Dn, __ATOMIC_RELAXED, __HIP_MEMORY_SCOPE_AGENT))
          break;
      }
    } else {
      for (int it = 0; it < (1 << 17); ++it) {
#pragma unroll 1
        for (int k = 0; k < 512; ++k)
          a0 = fmaf(a0, 1.0000001f, 1.0e-7f);
        asm volatile("" :: "v"(a0));
        if (__hip_atomic_load(Dn, __ATOMIC_RELAXED, __HIP_MEMORY_SCOPE_AGENT))
          break;
      }
    }
    return;
  }

  // ---- sc0 qualification: 8-round monotone ping-pong; timeout -> agent mode ----
  __shared__ int s_good;
  if (tid == 0) s_good = 1;
  __syncthreads();
  for (int r = 1; r <= 8; ++r) {
    if (tid == 0 && s_good) {
      drain_vm();
      st64_sc0(&Tst[b], (u64)r);
    }
    if (w == 0 && s_good) {
      int guard = 0;
      for (;;) {
        u64 v = (u64)r;
        if (l < G) v = ld64_sc0(&Tst[l]);
        bool ok = (l >= G) || (v >= (u64)r);
        if (__ballot((int)ok) == ~0ull) break;
        if (++guard > (1 << 12)) { if (l == 0) s_good = 0; break; }
      }
    }
    __syncthreads();
  }
  if (tid == 0)
    __hip_atomic_store(&Md[b], 2ull | (u64)s_good, __ATOMIC_RELEASE,
                       __HIP_MEMORY_SCOPE_AGENT);
  if (w == 0) {
    int guard = 0, moderes = 0;
    for (;;) {
      u64 v = 3ull;
      if (l < G) v = __hip_atomic_load(&Md[l], __ATOMIC_ACQUIRE,
                                       __HIP_MEMORY_SCOPE_AGENT);
      bool ok = (l >= G) || ((v & 2ull) != 0);
      if (__ballot((int)ok) == ~0ull) {
        u64 bm = __ballot((int)((v & 1ull) != 0));
        moderes = (bm == ~0ull) ? 1 : 0;
        break;
      }
      if (++guard > (1 << 20)) { moderes = 0; break; }
    }
    if (l == 0) s_i = moderes;
  }
  __syncthreads();
  const bool SC0F = (s_i != 0);      // block-uniform mode
  const int GSTEP = SC0F ? (1 << 12) : (1 << 22);

  // ================= body: R9 (agent data + sc0 spread flags) ===============

  const int pw   = (w >= 1) ? (w - 1) : 0;
  const int rloc = pw * 32 + (l >> 4) * 8;
  float wih[8][16];
  {
    int rbase = 96 * b + rloc;
    int cbase = 16 * (l & 15);
#pragma unroll
    for (int i = 0; i < 8; i++)
#pragma unroll
      for (int k = 0; k < 16; k++)
        wih[i][k] = W_ih[(size_t)(rbase + i) * NDIM + cbase + k];
  }
  float bihr[8];
#pragma unroll
  for (int i = 0; i < 8; i++) bihr[i] = b_ih[96 * b + rloc + i];

  float cw[4][16];
  {
    int rbase = 32 * b + w * 8 + (l >> 5) * 4;
    int cbase = 16 * (l & 31);
#pragma unroll
    for (int i = 0; i < 4; i++)
#pragma unroll
      for (int k = 0; k < 16; k++)
        cw[i][k] = C_w[(size_t)(rbase + i) * MDIM + cbase + k];
  }
  // hoist C_b off the per-step key path (was a global load every step)
  float cbr = 0.f;
  if (l < 32) cbr = C_b[32 * b + l];

  for (int i = tid; i < KP1; i += TPB) written[i] = 0u;
  if (tid == 0) bcw = 0u;
  hnew[tid]       = h0[tid];
  hnew[tid + 256] = h0[tid + 256];
  __syncthreads();

  float xreg[16];
  auto prefetchX = [&](int s) {
    int cbase = 16 * (l & 15);
    const float* xp = &X[(size_t)s * NDIM + cbase];
    if (SC0F) {
#pragma unroll
      for (int k = 0; k < 16; k++) xreg[k] = __builtin_nontemporal_load(&xp[k]);
    } else {
#pragma unroll
      for (int k = 0; k < 16; k++) xreg[k] = xp[k];
    }
  };

  auto produce_gi = [&](int s) {
    float p[8];
#pragma unroll
    for (int i = 0; i < 8; i++) {
      float a = 0.f;
#pragma unroll
      for (int k = 0; k < 16; k++) a = fmaf(wih[i][k], xreg[k], a);
      p[i] = a;
    }
#pragma unroll
    for (int off = 1; off <= 8; off <<= 1) {
#pragma unroll
      for (int i = 0; i < 8; i++) p[i] += __shfl_xor(p[i], off, 64);
    }
    if ((l & 15) == 0) {
      float* dst = &RING[(size_t)(s & 3) * 1536 + 96 * b + rloc];
#pragma unroll
      for (int i = 0; i < 8; i++) st_cohf(&dst[i], p[i] + bihr[i]);
    }
  };

  auto compute_gh = [&](float* dst) {
    int cb = 16 * (l & 31);
    float hr[16];
#pragma unroll
    for (int k = 0; k < 16; k += 4) *(float4*)&hr[k] = *(const float4*)&hnew[cb + k];
    int rb = 96 * b + w * 24 + (l >> 5) * 12;
    float p[12];
#pragma unroll
    for (int i = 0; i < 12; i++) {
      float a = 0.f;
      const float* wr = &W_hh[(size_t)(rb + i) * MDIM + cb];
#pragma unroll
      for (int k = 0; k < 16; k++) a = fmaf(wr[k], hr[k], a);
      p[i] = a;
    }
    int rl = w * 24 + (l >> 5) * 12;
    int lc = l & 31;
#pragma unroll
    for (int i = 0; i < 12; i++) red[(rl + i) * 36 + lc] = p[i];
    __syncthreads();
    if (tid < 96) {
      float a = 0.f;
#pragma unroll
      for (int k = 0; k < 32; k += 4) {
        float4 v = *(const float4*)&red[tid * 36 + k];
        a += v.x + v.y + v.z + v.w;
      }
      a += b_hh[96 * b + tid];
      st_cohf(&dst[96 * b + tid], a);
    }
    __syncthreads();   // compiler drains vmcnt before barrier -> data at MALL
  };

  // ---- startup ----
  if (w >= 1) {
    prefetchX(0); produce_gi(0);
    prefetchX(1); produce_gi(1);
    prefetchX(2); produce_gi(2);
    prefetchX(3);
  }
  __syncthreads();
  compute_gh(GHS);
  if (tid == 0) st_flag_rel(&F[b], 1ull);
  if (w == 0) {
    int guard = 0;
    for (;;) {
      u64 v = (l < G) ? ld_flag(&F[l]) : 1ull;
      if (__ballot((int)(v == 1ull)) == ~0ull) break;
      if (++guard > (1 << 22)) break;
    }
  }
  __syncthreads();

  const float* ghsrc = GHS;
  bool prevReadHit = false;
  int  qprev = 0;

  for (int t = 0; t < T_STEPS; ++t) {
    // ---- agent-scope load bundle ----
    float g0 = ld_cohf(&ghsrc[tid]);
    float g1 = ld_cohf(&ghsrc[tid + 256]);
    float g2 = ld_cohf(&ghsrc[512 + tid]);
    float g3 = ld_cohf(&ghsrc[512 + tid + 256]);
    float g4 = ld_cohf(&ghsrc[1024 + tid]);
    float g5 = ld_cohf(&ghsrc[1024 + tid + 256]);
    float m0 = 0.f, m1 = 0.f;
    if (prevReadHit) {
      m0 = ld_cohf(&Mrow[(size_t)qprev * 512 + tid]);
      m1 = ld_cohf(&Mrow[(size_t)qprev * 512 + tid + 256]);
    }
    const float* gi = &RING[(size_t)(t & 3) * 1536];
    float i0 = ld_cohf(&gi[tid]);
    float i1 = ld_cohf(&gi[tid + 256]);
    float i2 = ld_cohf(&gi[512 + tid]);
    float i3 = ld_cohf(&gi[512 + tid + 256]);
    float i4 = ld_cohf(&gi[1024 + tid]);
    float i5 = ld_cohf(&gi[1024 + tid + 256]);

    if (prevReadHit && b == 0) {
      __builtin_nontemporal_store(m0, &H[(size_t)(t - 1) * 512 + tid]);
      __builtin_nontemporal_store(m1, &H[(size_t)(t - 1) * 512 + tid + 256]);
    }

    float hp0 = prevReadHit ? m0 : hnew[tid];
    float hp1 = prevReadHit ? m1 : hnew[tid + 256];
    float r0 = sigm(i0 + g0), r1 = sigm(i1 + g1);
    float z0 = sigm(i2 + g2), z1 = sigm(i3 + g3);
    float n0 = tanh_(fmaf(r0, g4, i4)), n1 = tanh_(fmaf(r1, g5, i5));
    float hn0 = fmaf(z0, hp0 - n0, n0);
    float hn1 = fmaf(z1, hp1 - n1, n1);
    hnew[tid]       = hn0;
    hnew[tid + 256] = hn1;
    __syncthreads();                               // B1

    {
      int cb = 16 * (l & 31);
      float hr[16];
#pragma unroll
      for (int k = 0; k < 16; k += 4) *(float4*)&hr[k] = *(const float4*)&hnew[cb + k];
      float p0 = 0.f, p1 = 0.f, p2 = 0.f, p3 = 0.f;
#pragma unroll
      for (int k = 0; k < 16; k++) {
        p0 = fmaf(cw[0][k], hr[k], p0);
        p1 = fmaf(cw[1][k], hr[k], p1);
        p2 = fmaf(cw[2][k], hr[k], p2);
        p3 = fmaf(cw[3][k], hr[k], p3);
      }
      int rl = w * 8 + (l >> 5) * 4;
      int lc = l & 31;
      red[(rl + 0) * 36 + lc] = p0;
      red[(rl + 1) * 36 + lc] = p1;
      red[(rl + 2) * 36 + lc] = p2;
      red[(rl + 3) * 36 + lc] = p3;
    }
    __syncthreads();                               // B2

    u64 ownkey = 0;
    if (w <= 1) {
      u32 ord = 0;
      if (l < 32) {
        const float4* rp = (const float4*)&red[l * 36];
        float4 v0 = rp[0], v1 = rp[1], v2 = rp[2], v3 = rp[3];
        float4 v4 = rp[4], v5 = rp[5], v6 = rp[6], v7 = rp[7];
        double d0 = ((double)v0.x + (double)v0.y) + ((double)v0.z + (double)v0.w);
        double d1 = ((double)v1.x + (double)v1.y) + ((double)v1.z + (double)v1.w);
        double d2 = ((double)v2.x + (double)v2.y) + ((double)v2.z + (double)v2.w);
        double d3 = ((double)v3.x + (double)v3.y) + ((double)v3.z + (double)v3.w);
        double d4 = ((double)v4.x + (double)v4.y) + ((double)v4.z + (double)v4.w);
        double d5 = ((double)v5.x + (double)v5.y) + ((double)v5.z + (double)v5.w);
        double d6 = ((double)v6.x + (double)v6.y) + ((double)v6.z + (double)v6.w);
        double d7 = ((double)v7.x + (double)v7.y) + ((double)v7.z + (double)v7.w);
        double a = (((d0 + d1) + (d2 + d3)) + ((d4 + d5) + (d6 + d7)))
                 + (double)cbr;
        float af = (float)a;
        u32 bits = __float_as_uint(af);
        ord = (bits & 0x80000000u) ? ~bits : (bits | 0x80000000u);
      }
      u32 maxord = wave_max_u32(ord);
      u64 mask = __ballot((int)(ord == maxord));
      int lane = __builtin_ctzll(mask);
      u64 key41 = ((u64)maxord << 9) | (u64)(511 - (32 * b + lane));
      if (tid == 64) {
        u64 fv = ((u64)(t + 1) << 41) | key41;
        if (SC0F) st64_sc0(&FB1[((size_t)(t & 1) * 16 + b) * 16], fv);
        else      st_flag_rlx(&F[16 + (size_t)(t & 1) * 16 + b], fv);
      }
      ownkey = key41;
    }

    if (w >= 1 && t + 3 < T_STEPS) {
      produce_gi(t + 3);
      if (t + 4 < T_STEPS) prefetchX(t + 4);
    }

    u32 info;
    if (w == 0) {
      const bool need = (l < G) && (l != b);
      u64 v = 0;
      if (SC0F) {
        // ---- pipelined 2-deep sc0 poll ----
        drain_vm();
        const u64* fp = &FB1[((size_t)(t & 1) * 16 + l) * 16];
        u64 va = 0, vb = 0;
        if (need)
          asm volatile("global_load_dwordx2 %0, %2, off sc0\n\t"
                       "global_load_dwordx2 %1, %2, off sc0"
                       : "=&v"(va), "=&v"(vb) : "v"(fp) : "memory");
        int guard = 0;
        for (;;) {
          asm volatile("s_waitcnt vmcnt(1)" ::: "memory");
          bool ok = !need || ((va >> 41) == (u64)(t + 1));
          if (__ballot((int)ok) == ~0ull) { v = va; break; }
          if (need)
            asm volatile("global_load_dwordx2 %0, %1, off sc0"
                         : "=&v"(va) : "v"(fp) : "memory");
          asm volatile("s_waitcnt vmcnt(1)" ::: "memory");
          ok = !need || ((vb >> 41) == (u64)(t + 1));
          if (__ballot((int)ok) == ~0ull) { v = vb; break; }
          if (need)
            asm volatile("global_load_dwordx2 %0, %1, off sc0"
                         : "=&v"(vb) : "v"(fp) : "memory");
          if (++guard > GSTEP) { v = va; break; }
        }
        drain_vm();
      } else {
        const u64* fp = &F[16 + (size_t)(t & 1) * 16 + l];
        u64 vp = need ? ld_flag(fp) : 0;
        int guard = 0;
        for (;;) {
          u64 vn = need ? ld_flag(fp) : 0;
          bool ok = !need || ((vp >> 41) == (u64)(t + 1));
          if (__ballot((int)ok) == ~0ull) { v = vp; break; }
          vp = vn;
          if (++guard > GSTEP) { v = vp; break; }
        }
      }
      u64 key = (l < G) ? ((l == b) ? ownkey : (v & ((1ull << 41) - 1))) : 0;
      u32 o = (u32)(key >> 9);
      u32 maxo = row16_max_u32(o);
      u32 cand = (o == maxo && l < G) ? (u32)(key & 511u) : 0u;
      u32 best = row16_max_u32(cand);
      int q = 511 - (int)best;
      u32 vinfo = 0;
      if (l == 0) {
        u32 wr = written[q];
        u32 fresh = (q > 0 && wr == 0u) ? 1u : 0u;
        u32 rhit  = (q > 0 && wr != 0u) ? 1u : 0u;
        if (fresh) written[q] = 1u;
        vinfo = (u32)q | (fresh << 16) | (rhit << 17);
      }
      vinfo = (u32)__builtin_amdgcn_readfirstlane((int)vinfo);
      info = vinfo;
      if (l == 0)
        __hip_atomic_store(&bcw, (vinfo << 4) | ((u32)(t + 1) & 0xFu),
                           __ATOMIC_RELEASE, __HIP_MEMORY_SCOPE_WORKGROUP);
    } else {
      u32 v;
      int guard = 0;
      for (;;) {
        v = __hip_atomic_load(&bcw, __ATOMIC_ACQUIRE, __HIP_MEMORY_SCOPE_WORKGROUP);
        if ((v & 0xFu) == ((u32)(t + 1) & 0xFu)) break;
        if (++guard > (1 << 25)) break;
      }
      info = v >> 4;
    }
    int  q     = (int)(info & 0xFFFFu);
    bool fresh = (info >> 16) & 1u;
    bool rhit  = (info >> 17) & 1u;

    if (!rhit) {
      if (b == 0) {
        __builtin_nontemporal_store(hnew[tid], &H[(size_t)t * 512 + tid]);
        __builtin_nontemporal_store(hnew[tid + 256], &H[(size_t)t * 512 + tid + 256]);
      }
      float* dst;
      if (fresh) {
        if (tid < 32) st_cohf(&Mrow[(size_t)q * 512 + 32 * b + tid], hnew[32 * b + tid]);
        dst = &GH[(size_t)q * 1536];
      } else {
        dst = GHS;
      }
      compute_gh(dst);
      if (tid == 0) {
        if (SC0F) st64_sc0(&FC1[(size_t)b * 16], (u64)(t + 1));
        else      st_flag_rel(&F[48 + (size_t)(t & 1) * 16 + b], (u64)(t + 1));
      }
      if (w == 0) {
        int guard = 0;
        for (;;) {
          u64 v = (u64)(t + 1);
          if (l < G) {
            if (SC0F) v = ld64_sc0(&FC1[(size_t)l * 16]);
            else      v = ld_flag(&F[48 + (size_t)(t & 1) * 16 + l]);
          }
          bool ok = (l >= G) || (v == (u64)(t + 1));
          if (__ballot((int)ok) == ~0ull) break;
          if (++guard > GSTEP) break;
        }
      }
      __syncthreads();
      ghsrc = dst;
      prevReadHit = false;
    } else {
      ghsrc = &GH[(size_t)q * 1536];
      prevReadHit = true;
      qprev = q;
    }
  }

  // epilogue: H[T-1] for trailing read-hit (single writer)
  if (prevReadHit && b == 0) {
    float a = ld_cohf(&Mrow[(size_t)qprev * 512 + tid]);
    float c = ld_cohf(&Mrow[(size_t)qprev * 512 + tid + 256]);
    __builtin_nontemporal_store(a, &H[(size_t)(T_STEPS - 1) * 512 + tid]);
    __builtin_nontemporal_store(c, &H[(size_t)(T_STEPS - 1) * 512 + tid + 256]);
  }
  // release the keep-alive spinners
  if (b == 0 && tid == 0) st_flag_rel(Dn, 1ull);
}

// ---- V_w transpose (+ zero election scratch and mode-1 flag area) ----
__global__ void vw_transpose(const float* __restrict__ Vw, float* __restrict__ VwT) {
  int idx = blockIdx.x * 256 + threadIdx.x;
  if (blockIdx.x == 0) {
    float* M0 = VwT - (OFF_VWT - OFF_M);   // ws + OFF_M (row 0, never data)
    M0[threadIdx.x] = 0.f;
    M0[threadIdx.x + 256] = 0.f;
  }
  if (blockIdx.x == 1) {
    float* G0 = VwT - OFF_VWT;             // ws + OFF_GH (row 0, never data)
#pragma unroll
    for (int i = 0; i < 6; i++) G0[threadIdx.x + 256 * i] = 0.f;
  }
  int kk = idx >> 8, ll = idx & 255;
  VwT[idx] = Vw[(size_t)ll * MDIM + kk];
}

// ---- Y = H @ V_w^T + V_b ----
__global__ __launch_bounds__(256) void y_gemm(const float* __restrict__ Hm,
                                              const float* __restrict__ VwT,
                                              const float* __restrict__ Vb,
                                              float* __restrict__ Y) {
  int t0 = blockIdx.x * 16;
  int tid = threadIdx.x;
  __shared__ __align__(16) float hs[16 * MDIM];
  for (int i = tid; i < 16 * MDIM; i += 256)
    hs[i] = Hm[(size_t)t0 * MDIM + i];
  __syncthreads();
  float acc[16];
  float vb = Vb[tid];
#pragma unroll
  for (int r = 0; r < 16; r++) acc[r] = vb;
  for (int k = 0; k < MDIM; k += 4) {
    float v0 = VwT[(size_t)(k + 0) * LOUT + tid];
    float v1 = VwT[(size_t)(k + 1) * LOUT + tid];
    float v2 = VwT[(size_t)(k + 2) * LOUT + tid];
    float v3 = VwT[(size_t)(k + 3) * LOUT + tid];
#pragma unroll
    for (int r = 0; r < 16; r++) {
      float4 h4 = *(const float4*)&hs[r * MDIM + k];
      acc[r] = fmaf(h4.x, v0, fmaf(h4.y, v1, fmaf(h4.z, v2, fmaf(h4.w, v3, acc[r]))));
    }
  }
#pragma unroll
  for (int r = 0; r < 16; r++)
    Y[(size_t)(t0 + r) * LOUT + tid] = acc[r];
}

extern "C" void kernel_launch(void* const* d_in, const int* in_sizes, int n_in,
                              void* d_out, int out_size, void* d_ws, size_t ws_size,
                              hipStream_t stream) {
  const float* X    = (const float*)d_in[0];
  const float* h0   = (const float*)d_in[1];
  const float* W_ih = (const float*)d_in[2];
  const float* W_hh = (const float*)d_in[3];
  const float* b_ih = (const float*)d_in[4];
  const float* b_hh = (const float*)d_in[5];
  const float* C_w  = (const float*)d_in[6];
  const float* C_b  = (const float*)d_in[7];
  const float* V_w  = (const float*)d_in[8];
  const float* V_b  = (const float*)d_in[9];
  float* ws  = (float*)d_ws;
  float* VwT = ws + OFF_VWT;
  float* Hm  = ws + OFF_H;

  hipLaunchKernelGGL(vw_transpose, dim3(512), dim3(256), 0, stream, V_w, VwT);
  hipLaunchKernelGGL(dmm_main, dim3(NBLK), dim3(TPB), 0, stream,
                     X, h0, W_ih, W_hh, b_ih, b_hh, C_w, C_b, ws);
  hipLaunchKernelGGL(y_gemm, dim3(T_STEPS / 16), dim3(256), 0, stream,
                     Hm, VwT, V_b, (float*)d_out);
}

// Round 12
// 36288.983 us; speedup vs baseline: 1.0169x; 1.0099x over previous
//
#include <hip/hip_runtime.h>
#include <stdint.h>

#define T_STEPS 16384
#define NDIM 256
#define MDIM 512
#define KP1 512
#define LOUT 256
#define G 16
#define TPB 256
#define NBLK 256   // 1 block/CU; 16 workers on XCD 0; others = fabric keep-alive

typedef unsigned long long u64;
typedef unsigned int u32;

// ---- ws layout (float offsets) ----
constexpr size_t OFF_GH    = 0;                         // [512][1536] cached W_hh@M[q]+b_hh
constexpr size_t OFF_GHS   = 512ull * 1536;             // [1536] scratch gh (q==0 / startup)
constexpr size_t OFF_M     = OFF_GHS + 1536;            // [512][512] memory rows
constexpr size_t OFF_RING  = OFF_M + 512ull * 512;      // [4][1536] gi ring
constexpr size_t OFF_H     = OFF_RING + 4ull * 1536;    // [16384][512] hidden outputs
constexpr size_t OFF_VWT   = OFF_H + 16384ull * 512;    // [512][256] V_w transposed
constexpr size_t OFF_FLAGS = OFF_VWT + 512ull * 256;    // 80 u64 agent flags (in-bounds)
// GH row 0 (6144B, q==0 never data): mode-1 spread flags, one 128B line each:
//   FB1[(p*16+i)*16]  u64   FC1 = FB1+512 (u64 idx)
// Mrow row 0 (2048B, q==0 never data): election scratch + done flag:
//   Ecnt=(u32*)Mrow; Tst=(u64*)(Mrow+16); Md=(u64*)(Mrow+64); Dn=(u64*)Mrow+96

// ---- agent-scope (MALL) ops — data path (R6/R9-proven fastest) ----
__device__ __forceinline__ float ld_cohf(const float* p) {
  return __hip_atomic_load(p, __ATOMIC_RELAXED, __HIP_MEMORY_SCOPE_AGENT);
}
__device__ __forceinline__ void st_cohf(float* p, float v) {
  __hip_atomic_store(p, v, __ATOMIC_RELAXED, __HIP_MEMORY_SCOPE_AGENT);
}
__device__ __forceinline__ u64 ld_flag(const u64* p) {
  return __hip_atomic_load(p, __ATOMIC_RELAXED, __HIP_MEMORY_SCOPE_AGENT);
}
__device__ __forceinline__ void st_flag_rel(u64* p, u64 v) {
  __hip_atomic_store(p, v, __ATOMIC_RELEASE, __HIP_MEMORY_SCOPE_AGENT);
}
__device__ __forceinline__ void st_flag_rlx(u64* p, u64 v) {
  __hip_atomic_store(p, v, __ATOMIC_RELAXED, __HIP_MEMORY_SCOPE_AGENT);
}

// ---- sc0 (XCD-L2 coherence point) flag ops — only after qualification ----
__device__ __forceinline__ u64 ld64_sc0(const u64* p) {
  u64 v;
  asm volatile("global_load_dwordx2 %0, %1, off sc0\n\t"
               "s_waitcnt vmcnt(0)"
               : "=&v"(v) : "v"(p) : "memory");
  return v;
}
__device__ __forceinline__ void st64_sc0(u64* p, u64 v) {
  asm volatile("global_store_dwordx2 %0, %1, off sc0" :: "v"(p), "v"(v) : "memory");
}
__device__ __forceinline__ void drain_vm() {
  asm volatile("s_waitcnt vmcnt(0)" ::: "memory");
}

// HW_REG_XCC_ID = 20 (gfx940+)
#define HWREG_XCC_ID ((31u << 11) | 20u)
__device__ __forceinline__ u32 xcc_id() {
  return (u32)__builtin_amdgcn_s_getreg(HWREG_XCC_ID) & 0xFu;
}

__device__ __forceinline__ float sigm(float x) {
  return __builtin_amdgcn_rcpf(1.0f + __expf(-x));
}
__device__ __forceinline__ float tanh_(float x) {
  return 1.0f - 2.0f * __builtin_amdgcn_rcpf(__expf(2.0f * x) + 1.0f);
}

// ---- DPP max-reduce helpers ----
template<int CTRL>
__device__ __forceinline__ u32 dppmax(u32 v) {
  u32 t = (u32)__builtin_amdgcn_update_dpp(0, (int)v, CTRL, 0xf, 0xf, true);
  return v > t ? v : t;
}
__device__ __forceinline__ u32 wave_max_u32(u32 v) {
  v = dppmax<0x111>(v);
  v = dppmax<0x112>(v);
  v = dppmax<0x114>(v);
  v = dppmax<0x118>(v);
  v = dppmax<0x142>(v);
  v = dppmax<0x143>(v);
  return (u32)__builtin_amdgcn_readlane((int)v, 63);
}
__device__ __forceinline__ u32 row16_max_u32(u32 v) {
  v = dppmax<0x111>(v);
  v = dppmax<0x112>(v);
  v = dppmax<0x114>(v);
  v = dppmax<0x118>(v);
  return (u32)__builtin_amdgcn_readlane((int)v, 15);
}

__global__ __launch_bounds__(TPB, 1) void dmm_main(
    const float* __restrict__ X, const float* __restrict__ h0,
    const float* __restrict__ W_ih, const float* __restrict__ W_hh,
    const float* __restrict__ b_ih, const float* __restrict__ b_hh,
    const float* __restrict__ C_w, const float* __restrict__ C_b,
    float* __restrict__ ws)
{
  const int tid = threadIdx.x;
  const int w   = tid >> 6;
  const int l   = tid & 63;

  float* GH   = ws + OFF_GH;
  float* GHS  = ws + OFF_GHS;
  float* Mrow = ws + OFF_M;
  float* RING = ws + OFF_RING;
  float* H    = ws + OFF_H;
  u64*   F    = (u64*)(ws + OFF_FLAGS);
  u64*   FB1  = (u64*)(ws + OFF_GH);         // mode-1 spread flagB (GH row 0)
  u64*   FC1  = (u64*)(ws + OFF_GH) + 512;   // mode-1 spread flagC

  u32* Ecnt = (u32*)Mrow;
  u64* Tst  = (u64*)(Mrow + 16);
  u64* Md   = (u64*)(Mrow + 64);
  u64* Dn   = (u64*)Mrow + 96;               // done flag (byte 768, zeroed)

  __shared__ __align__(16) float hnew[MDIM];
  __shared__ __align__(16) float red[96 * 36];
  __shared__ u32 written[KP1];
  __shared__ u32 bcw;
  __shared__ int s_i;

  // ---- election: first G blocks on XCD 0 become workers ----
  if (tid == 0) {
    u32 xcc = xcc_id();
    int widx = -1;
    if (xcc == 0) {
      u32 r = __hip_atomic_fetch_add(Ecnt, 1u, __ATOMIC_RELAXED,
                                     __HIP_MEMORY_SCOPE_AGENT);
      if (r < (u32)G) widx = (int)r;
    } else if (blockIdx.x < G) {
      int guard = 0; u32 c;
      do {
        c = __hip_atomic_load(Ecnt, __ATOMIC_RELAXED, __HIP_MEMORY_SCOPE_AGENT);
      } while (c < (u32)G && ++guard < (1 << 12));
      if (c < (u32)G) {
        u32 r = __hip_atomic_fetch_add(Ecnt, 1u, __ATOMIC_RELAXED,
                                       __HIP_MEMORY_SCOPE_AGENT);
        if (r < (u32)G) widx = (int)r;
      }
    }
    s_i = widx;
  }
  __syncthreads();
  const int b = s_i;
  __syncthreads();

  if (b < 0) {
    // ---- keep-alive: pin the fabric (fixes gapped/profiled-mode FCLK droop) ----
    u32 xcc = xcc_id();
    float a0 = (float)(tid + 1) * 1.0e-3f;
    if (xcc != 0) {
      const char* xb = (const char*)X;
      float acc = 0.f;
      for (int it = 0; it < (1 << 17); ++it) {
        u32 off = ((u32)blockIdx.x * 2654435761u + (u32)it * 1664525u)
                  & 0x7FF000u;                       // 4KB-aligned, < 8MB
        const float* xp = (const float*)(xb + off + (u32)tid * 16u);
        float v0 = __builtin_nontemporal_load(&xp[0]);
        float v1 = __builtin_nontemporal_load(&xp[1]);
        float v2 = __builtin_nontemporal_load(&xp[2]);
        float v3 = __builtin_nontemporal_load(&xp[3]);
        acc += (v0 + v1) + (v2 + v3);
#pragma unroll 1
        for (int k = 0; k < 512; ++k)
          a0 = fmaf(a0, 1.0000001f, 1.0e-7f);
        asm volatile("" :: "v"(a0), "v"(acc));
        if (__hip_atomic_load(Dn, __ATOMIC_RELAXED, __HIP_MEMORY_SCOPE_AGENT))
          break;
      }
    } else {
      for (int it = 0; it < (1 << 17); ++it) {
#pragma unroll 1
        for (int k = 0; k < 512; ++k)
          a0 = fmaf(a0, 1.0000001f, 1.0e-7f);
        asm volatile("" :: "v"(a0));
        if (__hip_atomic_load(Dn, __ATOMIC_RELAXED, __HIP_MEMORY_SCOPE_AGENT))
          break;
      }
    }
    return;
  }

  // ---- sc0 qualification: 8-round monotone ping-pong; timeout -> agent mode ----
  __shared__ int s_good;
  if (tid == 0) s_good = 1;
  __syncthreads();
  for (int r = 1; r <= 8; ++r) {
    if (tid == 0 && s_good) {
      drain_vm();
      st64_sc0(&Tst[b], (u64)r);
    }
    if (w == 0 && s_good) {
      int guard = 0;
      for (;;) {
        u64 v = (u64)r;
        if (l < G) v = ld64_sc0(&Tst[l]);
        bool ok = (l >= G) || (v >= (u64)r);
        if (__ballot((int)ok) == ~0ull) break;
        if (++guard > (1 << 12)) { if (l == 0) s_good = 0; break; }
      }
    }
    __syncthreads();
  }
  if (tid == 0)
    __hip_atomic_store(&Md[b], 2ull | (u64)s_good, __ATOMIC_RELEASE,
                       __HIP_MEMORY_SCOPE_AGENT);
  if (w == 0) {
    int guard = 0, moderes = 0;
    for (;;) {
      u64 v = 3ull;
      if (l < G) v = __hip_atomic_load(&Md[l], __ATOMIC_ACQUIRE,
                                       __HIP_MEMORY_SCOPE_AGENT);
      bool ok = (l >= G) || ((v & 2ull) != 0);
      if (__ballot((int)ok) == ~0ull) {
        u64 bm = __ballot((int)((v & 1ull) != 0));
        moderes = (bm == ~0ull) ? 1 : 0;
        break;
      }
      if (++guard > (1 << 20)) { moderes = 0; break; }
    }
    if (l == 0) s_i = moderes;
  }
  __syncthreads();
  const bool SC0F = (s_i != 0);      // block-uniform mode
  const int GSTEP = SC0F ? (1 << 12) : (1 << 22);

  // ================= body: R11 + straggler-stall removal ====================

  const int pw   = (w >= 1) ? (w - 1) : 0;
  const int rloc = pw * 32 + (l >> 4) * 8;
  float wih[8][16];
  {
    int rbase = 96 * b + rloc;
    int cbase = 16 * (l & 15);
#pragma unroll
    for (int i = 0; i < 8; i++)
#pragma unroll
      for (int k = 0; k < 16; k++)
        wih[i][k] = W_ih[(size_t)(rbase + i) * NDIM + cbase + k];
  }
  float bihr[8];
#pragma unroll
  for (int i = 0; i < 8; i++) bihr[i] = b_ih[96 * b + rloc + i];

  float cw[4][16];
  {
    int rbase = 32 * b + w * 8 + (l >> 5) * 4;
    int cbase = 16 * (l & 31);
#pragma unroll
    for (int i = 0; i < 4; i++)
#pragma unroll
      for (int k = 0; k < 16; k++)
        cw[i][k] = C_w[(size_t)(rbase + i) * MDIM + cbase + k];
  }
  // hoisted C_b (off the per-step key path)
  float cbr = 0.f;
  if (l < 32) cbr = C_b[32 * b + l];

  for (int i = tid; i < KP1; i += TPB) written[i] = 0u;
  if (tid == 0) bcw = 0u;
  hnew[tid]       = h0[tid];
  hnew[tid + 256] = h0[tid + 256];
  __syncthreads();

  float xreg[16];
  auto prefetchX = [&](int s) {
    int cbase = 16 * (l & 15);
    const float* xp = &X[(size_t)s * NDIM + cbase];
    if (SC0F) {
#pragma unroll
      for (int k = 0; k < 16; k++) xreg[k] = __builtin_nontemporal_load(&xp[k]);
    } else {
#pragma unroll
      for (int k = 0; k < 16; k++) xreg[k] = xp[k];
    }
  };

  auto produce_gi = [&](int s) {
    float p[8];
#pragma unroll
    for (int i = 0; i < 8; i++) {
      float a = 0.f;
#pragma unroll
      for (int k = 0; k < 16; k++) a = fmaf(wih[i][k], xreg[k], a);
      p[i] = a;
    }
#pragma unroll
    for (int off = 1; off <= 8; off <<= 1) {
#pragma unroll
      for (int i = 0; i < 8; i++) p[i] += __shfl_xor(p[i], off, 64);
    }
    if ((l & 15) == 0) {
      float* dst = &RING[(size_t)(s & 3) * 1536 + 96 * b + rloc];
#pragma unroll
      for (int i = 0; i < 8; i++) st_cohf(&dst[i], p[i] + bihr[i]);
    }
  };

  auto compute_gh = [&](float* dst) {
    int cb = 16 * (l & 31);
    float hr[16];
#pragma unroll
    for (int k = 0; k < 16; k += 4) *(float4*)&hr[k] = *(const float4*)&hnew[cb + k];
    int rb = 96 * b + w * 24 + (l >> 5) * 12;
    float p[12];
#pragma unroll
    for (int i = 0; i < 12; i++) {
      float a = 0.f;
      const float* wr = &W_hh[(size_t)(rb + i) * MDIM + cb];
#pragma unroll
      for (int k = 0; k < 16; k++) a = fmaf(wr[k], hr[k], a);
      p[i] = a;
    }
    int rl = w * 24 + (l >> 5) * 12;
    int lc = l & 31;
#pragma unroll
    for (int i = 0; i < 12; i++) red[(rl + i) * 36 + lc] = p[i];
    __syncthreads();
    if (tid < 96) {
      float a = 0.f;
#pragma unroll
      for (int k = 0; k < 32; k += 4) {
        float4 v = *(const float4*)&red[tid * 36 + k];
        a += v.x + v.y + v.z + v.w;
      }
      a += b_hh[96 * b + tid];
      st_cohf(&dst[96 * b + tid], a);
    }
    __syncthreads();   // compiler drains vmcnt before barrier -> data at MALL
  };

  // ---- startup ----
  if (w >= 1) {
    prefetchX(0); produce_gi(0);
    prefetchX(1); produce_gi(1);
    prefetchX(2); produce_gi(2);
    prefetchX(3);
  }
  __syncthreads();
  compute_gh(GHS);
  if (tid == 0) st_flag_rel(&F[b], 1ull);
  if (w == 0) {
    int guard = 0;
    for (;;) {
      u64 v = (l < G) ? ld_flag(&F[l]) : 1ull;
      if (__ballot((int)(v == 1ull)) == ~0ull) break;
      if (++guard > (1 << 22)) break;
    }
  }
  __syncthreads();

  const float* ghsrc = GHS;
  bool prevReadHit = false;
  int  qprev = 0;

  for (int t = 0; t < T_STEPS; ++t) {
    // ---- agent-scope load bundle ----
    float g0 = ld_cohf(&ghsrc[tid]);
    float g1 = ld_cohf(&ghsrc[tid + 256]);
    float g2 = ld_cohf(&ghsrc[512 + tid]);
    float g3 = ld_cohf(&ghsrc[512 + tid + 256]);
    float g4 = ld_cohf(&ghsrc[1024 + tid]);
    float g5 = ld_cohf(&ghsrc[1024 + tid + 256]);
    // 4-wide M row load: dims (tid&127)+{0,128,256,384} (same row, one RTT).
    // Gives waves 2-3 the full 512-dim coverage needed for the H write.
    float mv0 = 0.f, mv1 = 0.f, mv2 = 0.f, mv3 = 0.f;
    if (prevReadHit) {
      const float* mp = &Mrow[(size_t)qprev * 512 + (tid & 127)];
      mv0 = ld_cohf(&mp[0]);
      mv1 = ld_cohf(&mp[128]);
      mv2 = ld_cohf(&mp[256]);
      mv3 = ld_cohf(&mp[384]);
    }
    const float* gi = &RING[(size_t)(t & 3) * 1536];
    float i0 = ld_cohf(&gi[tid]);
    float i1 = ld_cohf(&gi[tid + 256]);
    float i2 = ld_cohf(&gi[512 + tid]);
    float i3 = ld_cohf(&gi[512 + tid + 256]);
    float i4 = ld_cohf(&gi[1024 + tid]);
    float i5 = ld_cohf(&gi[1024 + tid + 256]);

    // lagged H write: waves 2-3 only, UNTRACKED asm nt stores.
    // Tracked stores forced a vmcnt(0) drain at B1 for block 0 only ->
    // per-hit-step straggler stall gating the whole 16-block ring.
    // Untracked stores skip the barrier drain; acks retire during the
    // exchange window (waves 2-3 have ~1000cy slack there).
    if (prevReadHit && b == 0 && w >= 2) {
      float* hdst = &H[(size_t)(t - 1) * 512 + (tid & 127)];
      asm volatile(
        "global_store_dword %0, %1, off nt\n\t"
        "global_store_dword %0, %2, off offset:512 nt\n\t"
        "global_store_dword %0, %3, off offset:1024 nt\n\t"
        "global_store_dword %0, %4, off offset:1536 nt"
        :: "v"(hdst), "v"(mv0), "v"(mv1), "v"(mv2), "v"(mv3)
        : "memory");
    }
    // wave-uniform dim selection: m0 = dim tid, m1 = dim tid+256
    float m0 = (tid < 128) ? mv0 : mv1;
    float m1 = (tid < 128) ? mv2 : mv3;

    float hp0 = prevReadHit ? m0 : hnew[tid];
    float hp1 = prevReadHit ? m1 : hnew[tid + 256];
    float r0 = sigm(i0 + g0), r1 = sigm(i1 + g1);
    float z0 = sigm(i2 + g2), z1 = sigm(i3 + g3);
    float n0 = tanh_(fmaf(r0, g4, i4)), n1 = tanh_(fmaf(r1, g5, i5));
    float hn0 = fmaf(z0, hp0 - n0, n0);
    float hn1 = fmaf(z1, hp1 - n1, n1);
    hnew[tid]       = hn0;
    hnew[tid + 256] = hn1;
    __syncthreads();                               // B1 (no store drain now)

    {
      int cb = 16 * (l & 31);
      float hr[16];
#pragma unroll
      for (int k = 0; k < 16; k += 4) *(float4*)&hr[k] = *(const float4*)&hnew[cb + k];
      float p0 = 0.f, p1 = 0.f, p2 = 0.f, p3 = 0.f;
#pragma unroll
      for (int k = 0; k < 16; k++) {
        p0 = fmaf(cw[0][k], hr[k], p0);
        p1 = fmaf(cw[1][k], hr[k], p1);
        p2 = fmaf(cw[2][k], hr[k], p2);
        p3 = fmaf(cw[3][k], hr[k], p3);
      }
      int rl = w * 8 + (l >> 5) * 4;
      int lc = l & 31;
      red[(rl + 0) * 36 + lc] = p0;
      red[(rl + 1) * 36 + lc] = p1;
      red[(rl + 2) * 36 + lc] = p2;
      red[(rl + 3) * 36 + lc] = p3;
    }
    __syncthreads();                               // B2

    u64 ownkey = 0;
    if (w <= 1) {
      u32 ord = 0;
      if (l < 32) {
        const float4* rp = (const float4*)&red[l * 36];
        float4 v0 = rp[0], v1 = rp[1], v2 = rp[2], v3 = rp[3];
        float4 v4 = rp[4], v5 = rp[5], v6 = rp[6], v7 = rp[7];
        double d0 = ((double)v0.x + (double)v0.y) + ((double)v0.z + (double)v0.w);
        double d1 = ((double)v1.x + (double)v1.y) + ((double)v1.z + (double)v1.w);
        double d2 = ((double)v2.x + (double)v2.y) + ((double)v2.z + (double)v2.w);
        double d3 = ((double)v3.x + (double)v3.y) + ((double)v3.z + (double)v3.w);
        double d4 = ((double)v4.x + (double)v4.y) + ((double)v4.z + (double)v4.w);
        double d5 = ((double)v5.x + (double)v5.y) + ((double)v5.z + (double)v5.w);
        double d6 = ((double)v6.x + (double)v6.y) + ((double)v6.z + (double)v6.w);
        double d7 = ((double)v7.x + (double)v7.y) + ((double)v7.z + (double)v7.w);
        double a = (((d0 + d1) + (d2 + d3)) + ((d4 + d5) + (d6 + d7)))
                 + (double)cbr;
        float af = (float)a;
        u32 bits = __float_as_uint(af);
        ord = (bits & 0x80000000u) ? ~bits : (bits | 0x80000000u);
      }
      u32 maxord = wave_max_u32(ord);
      u64 mask = __ballot((int)(ord == maxord));
      int lane = __builtin_ctzll(mask);
      u64 key41 = ((u64)maxord << 9) | (u64)(511 - (32 * b + lane));
      if (tid == 64) {
        u64 fv = ((u64)(t + 1) << 41) | key41;
        if (SC0F) st64_sc0(&FB1[((size_t)(t & 1) * 16 + b) * 16], fv);
        else      st_flag_rlx(&F[16 + (size_t)(t & 1) * 16 + b], fv);
      }
      ownkey = key41;
    }

    if (w >= 1 && t + 3 < T_STEPS) {
      produce_gi(t + 3);
      if (t + 4 < T_STEPS) prefetchX(t + 4);
    }

    u32 info;
    if (w == 0) {
      const bool need = (l < G) && (l != b);
      u64 v = 0;
      if (SC0F) {
        // ---- pipelined 2-deep sc0 poll (wave 0 has no stores outstanding) ----
        drain_vm();
        const u64* fp = &FB1[((size_t)(t & 1) * 16 + l) * 16];
        u64 va = 0, vb = 0;
        if (need)
          asm volatile("global_load_dwordx2 %0, %2, off sc0\n\t"
                       "global_load_dwordx2 %1, %2, off sc0"
                       : "=&v"(va), "=&v"(vb) : "v"(fp) : "memory");
        int guard = 0;
        for (;;) {
          asm volatile("s_waitcnt vmcnt(1)" ::: "memory");
          bool ok = !need || ((va >> 41) == (u64)(t + 1));
          if (__ballot((int)ok) == ~0ull) { v = va; break; }
          if (need)
            asm volatile("global_load_dwordx2 %0, %1, off sc0"
                         : "=&v"(va) : "v"(fp) : "memory");
          asm volatile("s_waitcnt vmcnt(1)" ::: "memory");
          ok = !need || ((vb >> 41) == (u64)(t + 1));
          if (__ballot((int)ok) == ~0ull) { v = vb; break; }
          if (need)
            asm volatile("global_load_dwordx2 %0, %1, off sc0"
                         : "=&v"(vb) : "v"(fp) : "memory");
          if (++guard > GSTEP) { v = va; break; }
        }
        drain_vm();
      } else {
        const u64* fp = &F[16 + (size_t)(t & 1) * 16 + l];
        u64 vp = need ? ld_flag(fp) : 0;
        int guard = 0;
        for (;;) {
          u64 vn = need ? ld_flag(fp) : 0;
          bool ok = !need || ((vp >> 41) == (u64)(t + 1));
          if (__ballot((int)ok) == ~0ull) { v = vp; break; }
          vp = vn;
          if (++guard > GSTEP) { v = vp; break; }
        }
      }
      u64 key = (l < G) ? ((l == b) ? ownkey : (v & ((1ull << 41) - 1))) : 0;
      u32 o = (u32)(key >> 9);
      u32 maxo = row16_max_u32(o);
      u32 cand = (o == maxo && l < G) ? (u32)(key & 511u) : 0u;
      u32 best = row16_max_u32(cand);
      int q = 511 - (int)best;
      u32 vinfo = 0;
      if (l == 0) {
        u32 wr = written[q];
        u32 fresh = (q > 0 && wr == 0u) ? 1u : 0u;
        u32 rhit  = (q > 0 && wr != 0u) ? 1u : 0u;
        if (fresh) written[q] = 1u;
        vinfo = (u32)q | (fresh << 16) | (rhit << 17);
      }
      vinfo = (u32)__builtin_amdgcn_readfirstlane((int)vinfo);
      info = vinfo;
      if (l == 0)
        __hip_atomic_store(&bcw, (vinfo << 4) | ((u32)(t + 1) & 0xFu),
                           __ATOMIC_RELEASE, __HIP_MEMORY_SCOPE_WORKGROUP);
    } else {
      u32 v;
      int guard = 0;
      for (;;) {
        v = __hip_atomic_load(&bcw, __ATOMIC_ACQUIRE, __HIP_MEMORY_SCOPE_WORKGROUP);
        if ((v & 0xFu) == ((u32)(t + 1) & 0xFu)) break;
        if (++guard > (1 << 25)) break;
      }
      info = v >> 4;
    }
    int  q     = (int)(info & 0xFFFFu);
    bool fresh = (info >> 16) & 1u;
    bool rhit  = (info >> 17) & 1u;

    if (!rhit) {
      if (b == 0) {
        __builtin_nontemporal_store(hnew[tid], &H[(size_t)t * 512 + tid]);
        __builtin_nontemporal_store(hnew[tid + 256], &H[(size_t)t * 512 + tid + 256]);
      }
      float* dst;
      if (fresh) {
        if (tid < 32) st_cohf(&Mrow[(size_t)q * 512 + 32 * b + tid], hnew[32 * b + tid]);
        dst = &GH[(size_t)q * 1536];
      } else {
        dst = GHS;
      }
      compute_gh(dst);
      if (tid == 0) {
        if (SC0F) st64_sc0(&FC1[(size_t)b * 16], (u64)(t + 1));
        else      st_flag_rel(&F[48 + (size_t)(t & 1) * 16 + b], (u64)(t + 1));
      }
      if (w == 0) {
        int guard = 0;
        for (;;) {
          u64 v = (u64)(t + 1);
          if (l < G) {
            if (SC0F) v = ld64_sc0(&FC1[(size_t)l * 16]);
            else      v = ld_flag(&F[48 + (size_t)(t & 1) * 16 + l]);
          }
          bool ok = (l >= G) || (v == (u64)(t + 1));
          if (__ballot((int)ok) == ~0ull) break;
          if (++guard > GSTEP) break;
        }
      }
      __syncthreads();
      ghsrc = dst;
      prevReadHit = false;
    } else {
      ghsrc = &GH[(size_t)q * 1536];
      prevReadHit = true;
      qprev = q;
    }
  }

  // epilogue: H[T-1] for trailing read-hit (single writer, tracked, once)
  if (prevReadHit && b == 0) {
    float a = ld_cohf(&Mrow[(size_t)qprev * 512 + tid]);
    float c = ld_cohf(&Mrow[(size_t)qprev * 512 + tid + 256]);
    __builtin_nontemporal_store(a, &H[(size_t)(T_STEPS - 1) * 512 + tid]);
    __builtin_nontemporal_store(c, &H[(size_t)(T_STEPS - 1) * 512 + tid + 256]);
  }
  drain_vm();   // retire untracked H stores before endpgm (visibility to y_gemm)
  // release the keep-alive spinners
  if (b == 0 && tid == 0) st_flag_rel(Dn, 1ull);
}

// ---- V_w transpose (+ zero election scratch and mode-1 flag area) ----
__global__ void vw_transpose(const float* __restrict__ Vw, float* __restrict__ VwT) {
  int idx = blockIdx.x * 256 + threadIdx.x;
  if (blockIdx.x == 0) {
    float* M0 = VwT - (OFF_VWT - OFF_M);   // ws + OFF_M (row 0, never data)
    M0[threadIdx.x] = 0.f;
    M0[threadIdx.x + 256] = 0.f;
  }
  if (blockIdx.x == 1) {
    float* G0 = VwT - OFF_VWT;             // ws + OFF_GH (row 0, never data)
#pragma unroll
    for (int i = 0; i < 6; i++) G0[threadIdx.x + 256 * i] = 0.f;
  }
  int kk = idx >> 8, ll = idx & 255;
  VwT[idx] = Vw[(size_t)ll * MDIM + kk];
}

// ---- Y = H @ V_w^T + V_b ----
__global__ __launch_bounds__(256) void y_gemm(const float* __restrict__ Hm,
                                              const float* __restrict__ VwT,
                                              const float* __restrict__ Vb,
                                              float* __restrict__ Y) {
  int t0 = blockIdx.x * 16;
  int tid = threadIdx.x;
  __shared__ __align__(16) float hs[16 * MDIM];
  for (int i = tid; i < 16 * MDIM; i += 256)
    hs[i] = Hm[(size_t)t0 * MDIM + i];
  __syncthreads();
  float acc[16];
  float vb = Vb[tid];
#pragma unroll
  for (int r = 0; r < 16; r++) acc[r] = vb;
  for (int k = 0; k < MDIM; k += 4) {
    float v0 = VwT[(size_t)(k + 0) * LOUT + tid];
    float v1 = VwT[(size_t)(k + 1) * LOUT + tid];
    float v2 = VwT[(size_t)(k + 2) * LOUT + tid];
    float v3 = VwT[(size_t)(k + 3) * LOUT + tid];
#pragma unroll
    for (int r = 0; r < 16; r++) {
      float4 h4 = *(const float4*)&hs[r * MDIM + k];
      acc[r] = fmaf(h4.x, v0, fmaf(h4.y, v1, fmaf(h4.z, v2, fmaf(h4.w, v3, acc[r]))));
    }
  }
#pragma unroll
  for (int r = 0; r < 16; r++)
    Y[(size_t)(t0 + r) * LOUT + tid] = acc[r];
}

extern "C" void kernel_launch(void* const* d_in, const int* in_sizes, int n_in,
                              void* d_out, int out_size, void* d_ws, size_t ws_size,
                              hipStream_t stream) {
  const float* X    = (const float*)d_in[0];
  const float* h0   = (const float*)d_in[1];
  const float* W_ih = (const float*)d_in[2];
  const float* W_hh = (const float*)d_in[3];
  const float* b_ih = (const float*)d_in[4];
  const float* b_hh = (const float*)d_in[5];
  const float* C_w  = (const float*)d_in[6];
  const float* C_b  = (const float*)d_in[7];
  const float* V_w  = (const float*)d_in[8];
  const float* V_b  = (const float*)d_in[9];
  float* ws  = (float*)d_ws;
  float* VwT = ws + OFF_VWT;
  float* Hm  = ws + OFF_H;

  hipLaunchKernelGGL(vw_transpose, dim3(512), dim3(256), 0, stream, V_w, VwT);
  hipLaunchKernelGGL(dmm_main, dim3(NBLK), dim3(TPB), 0, stream,
                     X, h0, W_ih, W_hh, b_ih, b_hh, C_w, C_b, ws);
  hipLaunchKernelGGL(y_gemm, dim3(T_STEPS / 16), dim3(256), 0, stream,
                     Hm, VwT, V_b, (float*)d_out);
}